// Round 1
// baseline (472.639 us; speedup 1.0000x reference)
//
#include <hip/hip_runtime.h>
#include <hip/hip_bf16.h>
#include <cstdint>
#include <cstddef>

using bf16 = __hip_bfloat16;
typedef __attribute__((ext_vector_type(8))) short bf16x8;
typedef __attribute__((ext_vector_type(4))) float f32x4;

#define TOKENS 4096
#define DMODEL 1024
#define DFF    4096
#define SEQ    2048
#define NHEAD  16
#define HDIM   64

__device__ __forceinline__ void async16(const void* g, void* l) {
  __builtin_amdgcn_global_load_lds(
      (const __attribute__((address_space(1))) void*)g,
      (__attribute__((address_space(3))) void*)l, 16, 0, 0);
}

__device__ __forceinline__ f32x4 mfma16(bf16x8 a, bf16x8 b, f32x4 c) {
  return __builtin_amdgcn_mfma_f32_16x16x32_bf16(a, b, c, 0, 0, 0);
}

// ---------------- prep: fp32 -> bf16 cast ----------------
__global__ void cast_bf16_k(const float* __restrict__ src, bf16* __restrict__ dst, int n) {
  int i = (blockIdx.x * blockDim.x + threadIdx.x) * 4;
  if (i >= n) return;
  float4 v = *(const float4*)(src + i);
  dst[i + 0] = __float2bfloat16(v.x);
  dst[i + 1] = __float2bfloat16(v.y);
  dst[i + 2] = __float2bfloat16(v.z);
  dst[i + 3] = __float2bfloat16(v.w);
}

// ---------------- prep: fp32 KxN -> bf16 NxK transpose ----------------
__global__ void transpose_cast_k(const float* __restrict__ src, bf16* __restrict__ dst,
                                 int K, int N) {
  __shared__ float tile[32][33];
  int nt = blockIdx.x * 32, kt = blockIdx.y * 32;
  int tx = threadIdx.x, ty = threadIdx.y;   // block (32,8)
  #pragma unroll
  for (int i = 0; i < 32; i += 8)
    tile[ty + i][tx] = src[(size_t)(kt + ty + i) * N + nt + tx];
  __syncthreads();
  #pragma unroll
  for (int i = 0; i < 32; i += 8)
    dst[(size_t)(nt + ty + i) * K + kt + tx] = __float2bfloat16(tile[tx][ty + i]);
}

// ---------------- GEMM: C[M][N] = A[M][K] * Bt[N][K] + bias, fused epilogue ----------------
// EPI 0: QKV scatter to Q/K/Vt bf16.  EPI 1: fp32 out = v + resid.  EPI 2: bf16 out = gelu(v).
template <int EPI>
__global__ __launch_bounds__(256, 2)
void gemm_bt(const bf16* __restrict__ A, const bf16* __restrict__ Bt,
             const float* __restrict__ bias, int M, int N, int K,
             float* __restrict__ outf, bf16* __restrict__ outb,
             const float* __restrict__ resid,
             bf16* __restrict__ Qb, bf16* __restrict__ Kb, bf16* __restrict__ Vtb) {
  __shared__ bf16 Al[128 * 32];
  __shared__ bf16 Bl[128 * 32];
  const int t = threadIdx.x;
  const int bm = blockIdx.y * 128, bn = blockIdx.x * 128;
  const int wid = t >> 6, lane = t & 63, g = lane >> 4, r = lane & 15;
  const int wr = (wid >> 1) * 64, wc = (wid & 1) * 64;

  const f32x4 zero = {0.f, 0.f, 0.f, 0.f};
  f32x4 acc[4][4];
  #pragma unroll
  for (int i = 0; i < 4; i++)
    #pragma unroll
    for (int j = 0; j < 4; j++) acc[i][j] = zero;

  const int ch0 = t, ch1 = t + 256;
  const int r0 = ch0 >> 2, c0 = (ch0 & 3) * 8;
  const int r1 = ch1 >> 2, c1 = (ch1 & 3) * 8;

  #pragma unroll 1
  for (int kt = 0; kt < K; kt += 32) {
    async16(A + (size_t)(bm + r0) * K + kt + c0, (char*)Al + ch0 * 16);
    async16(A + (size_t)(bm + r1) * K + kt + c1, (char*)Al + ch1 * 16);
    async16(Bt + (size_t)(bn + r0) * K + kt + c0, (char*)Bl + ch0 * 16);
    async16(Bt + (size_t)(bn + r1) * K + kt + c1, (char*)Bl + ch1 * 16);
    __syncthreads();   // drains vmcnt before barrier
    bf16x8 af[4], bfr[4];
    #pragma unroll
    for (int mt = 0; mt < 4; mt++) af[mt] = *(const bf16x8*)&Al[(wr + mt * 16 + r) * 32 + 8 * g];
    #pragma unroll
    for (int nt = 0; nt < 4; nt++) bfr[nt] = *(const bf16x8*)&Bl[(wc + nt * 16 + r) * 32 + 8 * g];
    #pragma unroll
    for (int mt = 0; mt < 4; mt++)
      #pragma unroll
      for (int nt = 0; nt < 4; nt++)
        acc[mt][nt] = mfma16(af[mt], bfr[nt], acc[mt][nt]);
    __syncthreads();
  }

  // epilogue: row = bm+wr+mt*16+4g+j, col = bn+wc+nt*16+r
  #pragma unroll
  for (int nt = 0; nt < 4; nt++) {
    const int col = bn + wc + nt * 16 + r;
    const float bv = bias[col];
    #pragma unroll
    for (int mt = 0; mt < 4; mt++) {
      #pragma unroll
      for (int j = 0; j < 4; j++) {
        const int row = bm + wr + mt * 16 + 4 * g + j;
        float v = acc[mt][nt][j] + bv;
        if constexpr (EPI == 0) {
          const int part = col >> 10, hd = col & 1023, h = hd >> 6, d = hd & 63;
          const int b_ = row >> 11, s_ = row & 2047;
          const bf16 q = __float2bfloat16(v);
          if (part == 0)      Qb[((size_t)(b_ * NHEAD + h) * SEQ + s_) * HDIM + d] = q;
          else if (part == 1) Kb[((size_t)(b_ * NHEAD + h) * SEQ + s_) * HDIM + d] = q;
          else                Vtb[((size_t)(b_ * NHEAD + h) * HDIM + d) * SEQ + s_] = q;
        } else if constexpr (EPI == 1) {
          const size_t idx = (size_t)row * N + col;
          outf[idx] = v + resid[idx];
        } else {
          const size_t idx = (size_t)row * N + col;
          outb[idx] = __float2bfloat16(0.5f * v * (1.f + erff(v * 0.70710678118f)));
        }
      }
    }
  }
}

// ---------------- flash attention (full, no mask) ----------------
// grid (32 bh, 32 qblocks), 256 thr = 4 waves, each wave owns 16 q rows.
__global__ __launch_bounds__(256, 2)
void attn_k(const bf16* __restrict__ Q, const bf16* __restrict__ Km,
            const bf16* __restrict__ Vt, bf16* __restrict__ O) {
  __shared__ bf16 P[4][16 * 32];
  const int bh = blockIdx.x, qb = blockIdx.y;
  const int t = threadIdx.x, wid = t >> 6, lane = t & 63, g = lane >> 4, r = lane & 15;
  const int q0 = qb * 64 + wid * 16;
  const bf16* Qp = Q + (size_t)bh * SEQ * HDIM;
  const bf16* Kp = Km + (size_t)bh * SEQ * HDIM;
  const bf16* Vp = Vt + (size_t)bh * HDIM * SEQ;

  const bf16x8 qf0 = *(const bf16x8*)&Qp[(q0 + r) * HDIM + 8 * g];
  const bf16x8 qf1 = *(const bf16x8*)&Qp[(q0 + r) * HDIM + 8 * g + 32];

  const f32x4 zero = {0.f, 0.f, 0.f, 0.f};
  f32x4 oacc[4];
  #pragma unroll
  for (int i = 0; i < 4; i++) oacc[i] = zero;
  float mrow[4] = {-1e30f, -1e30f, -1e30f, -1e30f};
  float lrow[4] = {0.f, 0.f, 0.f, 0.f};
  bf16* pl = P[wid];

  #pragma unroll 1
  for (int kt = 0; kt < SEQ; kt += 32) {
    bf16x8 k0a = *(const bf16x8*)&Kp[(kt + r) * HDIM + 8 * g];
    bf16x8 k0b = *(const bf16x8*)&Kp[(kt + r) * HDIM + 8 * g + 32];
    bf16x8 k1a = *(const bf16x8*)&Kp[(kt + 16 + r) * HDIM + 8 * g];
    bf16x8 k1b = *(const bf16x8*)&Kp[(kt + 16 + r) * HDIM + 8 * g + 32];
    f32x4 s0 = zero, s1 = zero;
    s0 = mfma16(qf0, k0a, s0);
    s0 = mfma16(qf1, k0b, s0);
    s1 = mfma16(qf0, k1a, s1);
    s1 = mfma16(qf1, k1b, s1);

    float corr[4];
    #pragma unroll
    for (int j = 0; j < 4; j++) {
      float a0 = s0[j] * 0.125f, a1 = s1[j] * 0.125f;
      float mx = fmaxf(a0, a1);
      mx = fmaxf(mx, __shfl_xor(mx, 1));
      mx = fmaxf(mx, __shfl_xor(mx, 2));
      mx = fmaxf(mx, __shfl_xor(mx, 4));
      mx = fmaxf(mx, __shfl_xor(mx, 8));
      const float mn = fmaxf(mrow[j], mx);
      corr[j] = __expf(mrow[j] - mn);
      mrow[j] = mn;
      a0 = __expf(a0 - mn);
      a1 = __expf(a1 - mn);
      float sm = a0 + a1;
      sm += __shfl_xor(sm, 1);
      sm += __shfl_xor(sm, 2);
      sm += __shfl_xor(sm, 4);
      sm += __shfl_xor(sm, 8);
      lrow[j] = lrow[j] * corr[j] + sm;
      pl[(4 * g + j) * 32 + r]      = __float2bfloat16(a0);
      pl[(4 * g + j) * 32 + 16 + r] = __float2bfloat16(a1);
    }
    asm volatile("s_waitcnt lgkmcnt(0)" ::: "memory");  // wave-internal LDS fence
    const bf16x8 pf = *(const bf16x8*)&pl[r * 32 + 8 * g];
    #pragma unroll
    for (int dt = 0; dt < 4; dt++) {
      bf16x8 vf = *(const bf16x8*)&Vp[(dt * 16 + r) * SEQ + kt + 8 * g];
      #pragma unroll
      for (int j = 0; j < 4; j++) oacc[dt][j] *= corr[j];
      oacc[dt] = mfma16(pf, vf, oacc[dt]);
    }
  }

  const int b_ = bh >> 4, h = bh & 15;
  #pragma unroll
  for (int dt = 0; dt < 4; dt++)
    #pragma unroll
    for (int j = 0; j < 4; j++) {
      const int tok = b_ * SEQ + q0 + 4 * g + j;
      O[(size_t)tok * DMODEL + h * HDIM + dt * 16 + r] =
          __float2bfloat16(oacc[dt][j] / lrow[j]);
    }
}

// ---------------- LayerNorm (one block per row of 1024) ----------------
__global__ __launch_bounds__(256)
void ln_k(const float* __restrict__ in, const float* __restrict__ gw,
          const float* __restrict__ bw, float* __restrict__ outf,
          bf16* __restrict__ outb) {
  const int row = blockIdx.x, t = threadIdx.x;
  const float4 v = *(const float4*)(in + (size_t)row * DMODEL + t * 4);
  float s = v.x + v.y + v.z + v.w;
  float s2 = v.x * v.x + v.y * v.y + v.z * v.z + v.w * v.w;
  #pragma unroll
  for (int m = 1; m < 64; m <<= 1) { s += __shfl_xor(s, m); s2 += __shfl_xor(s2, m); }
  __shared__ float red[8];
  const int wid = t >> 6, lane = t & 63;
  if (lane == 0) { red[wid] = s; red[4 + wid] = s2; }
  __syncthreads();
  s = red[0] + red[1] + red[2] + red[3];
  s2 = red[4] + red[5] + red[6] + red[7];
  const float mu = s * (1.f / DMODEL);
  const float rstd = rsqrtf(s2 * (1.f / DMODEL) - mu * mu + 1e-5f);
  const float4 gv = *(const float4*)(gw + t * 4);
  const float4 bv = *(const float4*)(bw + t * 4);
  float o0 = (v.x - mu) * rstd * gv.x + bv.x;
  float o1 = (v.y - mu) * rstd * gv.y + bv.y;
  float o2 = (v.z - mu) * rstd * gv.z + bv.z;
  float o3 = (v.w - mu) * rstd * gv.w + bv.w;
  if (outf) {
    float4 ov = {o0, o1, o2, o3};
    *(float4*)(outf + (size_t)row * DMODEL + t * 4) = ov;
  }
  if (outb) {
    bf16* p = outb + (size_t)row * DMODEL + t * 4;
    p[0] = __float2bfloat16(o0); p[1] = __float2bfloat16(o1);
    p[2] = __float2bfloat16(o2); p[3] = __float2bfloat16(o3);
  }
}

extern "C" void kernel_launch(void* const* d_in, const int* in_sizes, int n_in,
                              void* d_out, int out_size, void* d_ws, size_t ws_size,
                              hipStream_t stream) {
  const float* x     = (const float*)d_in[0];
  const float* w_qkv = (const float*)d_in[1];
  const float* b_qkv = (const float*)d_in[2];
  const float* w_out = (const float*)d_in[3];
  const float* b_out = (const float*)d_in[4];
  const float* w_ff1 = (const float*)d_in[5];
  const float* b_ff1 = (const float*)d_in[6];
  const float* w_ff2 = (const float*)d_in[7];
  const float* b_ff2 = (const float*)d_in[8];
  const float* ln1_g = (const float*)d_in[9];
  const float* ln1_b = (const float*)d_in[10];
  const float* ln2_g = (const float*)d_in[11];
  const float* ln2_b = (const float*)d_in[12];
  float* out = (float*)d_out;

  // workspace layout (96 MiB; hb aliases the dead Q/K/Vt/xob pool)
  char* base = (char*)d_ws;
  bf16* wqkvT = (bf16*)(base);                 //  6291456 : 3072x1024
  bf16* woutT = (bf16*)(base + 6291456);       //  2097152 : 1024x1024
  bf16* wff1T = (bf16*)(base + 8388608);       //  8388608 : 4096x1024
  bf16* wff2T = (bf16*)(base + 16777216);      //  8388608 : 1024x4096
  bf16* Qb    = (bf16*)(base + 25165824);      //  8388608
  bf16* Kb    = (bf16*)(base + 33554432);      //  8388608
  bf16* Vtb   = (bf16*)(base + 41943040);      //  8388608
  bf16* xob   = (bf16*)(base + 50331648);      //  8388608 : x_bf16, later attn-out bf16
  bf16* hb    = (bf16*)(base + 25165824);      // 33554432 : aliases Qb..xob (dead by FF1)
  float* y    = (float*)(base + 58720256);     // 16777216 : y1 then y2
  float* x1f  = (float*)(base + 75497472);     // 16777216
  bf16* x1b   = (bf16*)(base + 92274688);      //  8388608
  (void)in_sizes; (void)n_in; (void)out_size; (void)ws_size;

  dim3 tb(32, 8);
  // prep: transpose weights to bf16 N x K, cast x to bf16
  transpose_cast_k<<<dim3(3072 / 32, 1024 / 32), tb, 0, stream>>>(w_qkv, wqkvT, 1024, 3072);
  transpose_cast_k<<<dim3(1024 / 32, 1024 / 32), tb, 0, stream>>>(w_out, woutT, 1024, 1024);
  transpose_cast_k<<<dim3(4096 / 32, 1024 / 32), tb, 0, stream>>>(w_ff1, wff1T, 1024, 4096);
  transpose_cast_k<<<dim3(1024 / 32, 4096 / 32), tb, 0, stream>>>(w_ff2, wff2T, 4096, 1024);
  cast_bf16_k<<<(TOKENS * DMODEL / 4 + 255) / 256, 256, 0, stream>>>(x, xob, TOKENS * DMODEL);

  // QKV projection + scatter
  gemm_bt<0><<<dim3(3072 / 128, TOKENS / 128), 256, 0, stream>>>(
      xob, wqkvT, b_qkv, TOKENS, 3072, 1024, nullptr, nullptr, nullptr, Qb, Kb, Vtb);
  // attention
  attn_k<<<dim3(32, 32), 256, 0, stream>>>(Qb, Kb, Vtb, xob);
  // out projection + residual (fp32 x)
  gemm_bt<1><<<dim3(1024 / 128, TOKENS / 128), 256, 0, stream>>>(
      xob, woutT, b_out, TOKENS, 1024, 1024, y, nullptr, x, nullptr, nullptr, nullptr);
  // LN1 -> x1 (fp32 + bf16)
  ln_k<<<TOKENS, 256, 0, stream>>>(y, ln1_g, ln1_b, x1f, x1b);
  // FF1 + GELU
  gemm_bt<2><<<dim3(4096 / 128, TOKENS / 128), 256, 0, stream>>>(
      x1b, wff1T, b_ff1, TOKENS, 4096, 1024, nullptr, hb, nullptr, nullptr, nullptr, nullptr);
  // FF2 + residual (fp32 x1)
  gemm_bt<1><<<dim3(1024 / 128, TOKENS / 128), 256, 0, stream>>>(
      hb, wff2T, b_ff2, TOKENS, 1024, 4096, y, nullptr, x1f, nullptr, nullptr, nullptr);
  // LN2 -> d_out
  ln_k<<<TOKENS, 256, 0, stream>>>(y, ln2_g, ln2_b, out, nullptr);
}

// Round 2
// 471.499 us; speedup vs baseline: 1.0024x; 1.0024x over previous
//
#include <hip/hip_runtime.h>
#include <hip/hip_bf16.h>
#include <cstdint>
#include <cstddef>

using bf16 = __hip_bfloat16;
typedef __attribute__((ext_vector_type(8))) short bf16x8;
typedef __attribute__((ext_vector_type(4))) float f32x4;

#define TOKENS 4096
#define DMODEL 1024
#define DFF    4096
#define SEQ    2048
#define NHEAD  16
#define HDIM   64

__device__ __forceinline__ void async16(const void* g, void* l) {
  __builtin_amdgcn_global_load_lds(
      (const __attribute__((address_space(1))) void*)g,
      (__attribute__((address_space(3))) void*)l, 16, 0, 0);
}

__device__ __forceinline__ f32x4 mfma16(bf16x8 a, bf16x8 b, f32x4 c) {
  return __builtin_amdgcn_mfma_f32_16x16x32_bf16(a, b, c, 0, 0, 0);
}

// ---------------- prep: fp32 -> bf16 cast ----------------
__global__ void cast_bf16_k(const float* __restrict__ src, bf16* __restrict__ dst, int n) {
  int i = (blockIdx.x * blockDim.x + threadIdx.x) * 4;
  if (i >= n) return;
  float4 v = *(const float4*)(src + i);
  dst[i + 0] = __float2bfloat16(v.x);
  dst[i + 1] = __float2bfloat16(v.y);
  dst[i + 2] = __float2bfloat16(v.z);
  dst[i + 3] = __float2bfloat16(v.w);
}

// ---------------- prep: fp32 KxN -> bf16 NxK transpose ----------------
__global__ void transpose_cast_k(const float* __restrict__ src, bf16* __restrict__ dst,
                                 int K, int N) {
  __shared__ float tile[32][33];
  int nt = blockIdx.x * 32, kt = blockIdx.y * 32;
  int tx = threadIdx.x, ty = threadIdx.y;   // block (32,8)
  #pragma unroll
  for (int i = 0; i < 32; i += 8)
    tile[ty + i][tx] = src[(size_t)(kt + ty + i) * N + nt + tx];
  __syncthreads();
  #pragma unroll
  for (int i = 0; i < 32; i += 8)
    dst[(size_t)(nt + ty + i) * K + kt + tx] = __float2bfloat16(tile[tx][ty + i]);
}

// ---------------- GEMM: C[M][N] = A[M][K] * Bt[N][K] + bias, fused epilogue ----------------
// EPI 0: QKV scatter to Q/K/Vt bf16.  EPI 1: fp32 out = v + resid.  EPI 2: bf16 out = gelu(v).
template <int EPI>
__global__ __launch_bounds__(256, 2)
void gemm_bt(const bf16* __restrict__ A, const bf16* __restrict__ Bt,
             const float* __restrict__ bias, int M, int N, int K,
             float* __restrict__ outf, bf16* __restrict__ outb,
             const float* __restrict__ resid,
             bf16* __restrict__ Qb, bf16* __restrict__ Kb, bf16* __restrict__ Vtb) {
  __shared__ bf16 Al[128 * 32];
  __shared__ bf16 Bl[128 * 32];
  const int t = threadIdx.x;
  const int bm = blockIdx.y * 128, bn = blockIdx.x * 128;
  const int wid = t >> 6, lane = t & 63, g = lane >> 4, r = lane & 15;
  const int wr = (wid >> 1) * 64, wc = (wid & 1) * 64;

  const f32x4 zero = {0.f, 0.f, 0.f, 0.f};
  f32x4 acc[4][4];
  #pragma unroll
  for (int i = 0; i < 4; i++)
    #pragma unroll
    for (int j = 0; j < 4; j++) acc[i][j] = zero;

  const int ch0 = t, ch1 = t + 256;
  const int r0 = ch0 >> 2, c0 = (ch0 & 3) * 8;
  const int r1 = ch1 >> 2, c1 = (ch1 & 3) * 8;

  #pragma unroll 1
  for (int kt = 0; kt < K; kt += 32) {
    async16(A + (size_t)(bm + r0) * K + kt + c0, (char*)Al + ch0 * 16);
    async16(A + (size_t)(bm + r1) * K + kt + c1, (char*)Al + ch1 * 16);
    async16(Bt + (size_t)(bn + r0) * K + kt + c0, (char*)Bl + ch0 * 16);
    async16(Bt + (size_t)(bn + r1) * K + kt + c1, (char*)Bl + ch1 * 16);
    __syncthreads();   // drains vmcnt before barrier
    bf16x8 af[4], bfr[4];
    #pragma unroll
    for (int mt = 0; mt < 4; mt++) af[mt] = *(const bf16x8*)&Al[(wr + mt * 16 + r) * 32 + 8 * g];
    #pragma unroll
    for (int nt = 0; nt < 4; nt++) bfr[nt] = *(const bf16x8*)&Bl[(wc + nt * 16 + r) * 32 + 8 * g];
    #pragma unroll
    for (int mt = 0; mt < 4; mt++)
      #pragma unroll
      for (int nt = 0; nt < 4; nt++)
        acc[mt][nt] = mfma16(af[mt], bfr[nt], acc[mt][nt]);
    __syncthreads();
  }

  // epilogue: row = bm+wr+mt*16+4g+j, col = bn+wc+nt*16+r
  #pragma unroll
  for (int nt = 0; nt < 4; nt++) {
    const int col = bn + wc + nt * 16 + r;
    const float bv = bias[col];
    #pragma unroll
    for (int mt = 0; mt < 4; mt++) {
      #pragma unroll
      for (int j = 0; j < 4; j++) {
        const int row = bm + wr + mt * 16 + 4 * g + j;
        float v = acc[mt][nt][j] + bv;
        if constexpr (EPI == 0) {
          const int part = col >> 10, hd = col & 1023, h = hd >> 6, d = hd & 63;
          const int b_ = row >> 11, s_ = row & 2047;
          const bf16 q = __float2bfloat16(v);
          if (part == 0)      Qb[((size_t)(b_ * NHEAD + h) * SEQ + s_) * HDIM + d] = q;
          else if (part == 1) Kb[((size_t)(b_ * NHEAD + h) * SEQ + s_) * HDIM + d] = q;
          else                Vtb[((size_t)(b_ * NHEAD + h) * HDIM + d) * SEQ + s_] = q;
        } else if constexpr (EPI == 1) {
          const size_t idx = (size_t)row * N + col;
          outf[idx] = v + resid[idx];
        } else {
          const size_t idx = (size_t)row * N + col;
          outb[idx] = __float2bfloat16(0.5f * v * (1.f + erff(v * 0.70710678118f)));
        }
      }
    }
  }
}

// ---------------- flash attention, swapped-QK^T (full, no mask) ----------------
// grid (32 bh, 32 qblocks), 256 thr = 4 waves, each wave owns 16 q rows, KVBLK=64.
// S = mfma(K_frag, Q_frag) -> S[k = 4g+j][q = r]: each lane holds 16 k-values of ONE
// q-row -> row reduce = in-register tree + shfl_xor(16), shfl_xor(32).
__global__ __launch_bounds__(256, 4)
void attn_k(const bf16* __restrict__ Q, const bf16* __restrict__ Km,
            const bf16* __restrict__ Vt, bf16* __restrict__ O) {
  __shared__ bf16 P[4][16 * 72];          // per-wave P tile [16 q][64 k], stride 72 pads banks
  const int bh = blockIdx.x, qb = blockIdx.y;
  const int t = threadIdx.x, wid = t >> 6, lane = t & 63, g = lane >> 4, r = lane & 15;
  const int q0 = qb * 64 + wid * 16;
  const bf16* Qp = Q + (size_t)bh * SEQ * HDIM;
  const bf16* Kp = Km + (size_t)bh * SEQ * HDIM;
  const bf16* Vp = Vt + (size_t)bh * HDIM * SEQ;

  // Q B-fragments: col=q=r, k-elems d = 8g+e (+32)
  const bf16x8 qf0 = *(const bf16x8*)&Qp[(q0 + r) * HDIM + 8 * g];
  const bf16x8 qf1 = *(const bf16x8*)&Qp[(q0 + r) * HDIM + 8 * g + 32];

  const f32x4 zero = {0.f, 0.f, 0.f, 0.f};
  f32x4 oacc[4];
  #pragma unroll
  for (int i = 0; i < 4; i++) oacc[i] = zero;
  float mrow = -1e30f, lrow = 0.f;
  bf16* pl = P[wid];

  #pragma unroll 1
  for (int kt0 = 0; kt0 < SEQ; kt0 += 64) {
    // ---- QK^T (swapped): A = K rows, B = Q ----
    f32x4 sacc[4];
    #pragma unroll
    for (int kt = 0; kt < 4; kt++) {
      bf16x8 ka = *(const bf16x8*)&Kp[(kt0 + kt * 16 + r) * HDIM + 8 * g];
      bf16x8 kb = *(const bf16x8*)&Kp[(kt0 + kt * 16 + r) * HDIM + 8 * g + 32];
      f32x4 s = zero;
      s = mfma16(ka, qf0, s);
      s = mfma16(kb, qf1, s);
      sacc[kt] = s;
    }

    // ---- softmax: 16 per-lane values, one q-row (q = r) ----
    float sv[4][4];
    #pragma unroll
    for (int kt = 0; kt < 4; kt++)
      #pragma unroll
      for (int j = 0; j < 4; j++) sv[kt][j] = sacc[kt][j] * 0.125f;
    float m0 = fmaxf(fmaxf(sv[0][0], sv[0][1]), fmaxf(sv[0][2], sv[0][3]));
    float m1 = fmaxf(fmaxf(sv[1][0], sv[1][1]), fmaxf(sv[1][2], sv[1][3]));
    float m2 = fmaxf(fmaxf(sv[2][0], sv[2][1]), fmaxf(sv[2][2], sv[2][3]));
    float m3 = fmaxf(fmaxf(sv[3][0], sv[3][1]), fmaxf(sv[3][2], sv[3][3]));
    float mx = fmaxf(fmaxf(m0, m1), fmaxf(m2, m3));
    mx = fmaxf(mx, __shfl_xor(mx, 16));
    mx = fmaxf(mx, __shfl_xor(mx, 32));
    const float mn = fmaxf(mrow, mx);
    const float corr = __expf(mrow - mn);
    mrow = mn;
    float sum = 0.f;
    #pragma unroll
    for (int kt = 0; kt < 4; kt++)
      #pragma unroll
      for (int j = 0; j < 4; j++) {
        const float p = __expf(sv[kt][j] - mn);
        sv[kt][j] = p;
        sum += p;
      }
    sum += __shfl_xor(sum, 16);
    sum += __shfl_xor(sum, 32);
    lrow = lrow * corr + sum;

    // ---- P -> LDS (bf16), then read back as PV A-fragments ----
    #pragma unroll
    for (int kt = 0; kt < 4; kt++) {
      bf16 pk[4] = {__float2bfloat16(sv[kt][0]), __float2bfloat16(sv[kt][1]),
                    __float2bfloat16(sv[kt][2]), __float2bfloat16(sv[kt][3])};
      *(short4*)&pl[r * 72 + kt * 16 + 4 * g] = *(const short4*)pk;
    }
    asm volatile("s_waitcnt lgkmcnt(0)" ::: "memory");  // wave-internal LDS fence
    const bf16x8 pf0 = *(const bf16x8*)&pl[r * 72 + 8 * g];
    const bf16x8 pf1 = *(const bf16x8*)&pl[r * 72 + 32 + 8 * g];

    // corr for this lane's O rows (q_local = 4g+j lives at lane 4g+j)
    float cq[4];
    #pragma unroll
    for (int j = 0; j < 4; j++) cq[j] = __shfl(corr, 4 * g + j);

    // ---- PV: A = P rows (q), B = Vt rows (d) ----
    #pragma unroll
    for (int dt = 0; dt < 4; dt++) {
      #pragma unroll
      for (int j = 0; j < 4; j++) oacc[dt][j] *= cq[j];
      bf16x8 v0 = *(const bf16x8*)&Vp[(dt * 16 + r) * SEQ + kt0 + 8 * g];
      bf16x8 v1 = *(const bf16x8*)&Vp[(dt * 16 + r) * SEQ + kt0 + 32 + 8 * g];
      oacc[dt] = mfma16(pf0, v0, oacc[dt]);
      oacc[dt] = mfma16(pf1, v1, oacc[dt]);
    }
  }

  float lq[4];
  #pragma unroll
  for (int j = 0; j < 4; j++) lq[j] = __shfl(lrow, 4 * g + j);
  const int b_ = bh >> 4, h = bh & 15;
  #pragma unroll
  for (int dt = 0; dt < 4; dt++)
    #pragma unroll
    for (int j = 0; j < 4; j++) {
      const int tok = b_ * SEQ + q0 + 4 * g + j;
      O[(size_t)tok * DMODEL + h * HDIM + dt * 16 + r] =
          __float2bfloat16(oacc[dt][j] / lq[j]);
    }
}

// ---------------- LayerNorm (one block per row of 1024) ----------------
__global__ __launch_bounds__(256)
void ln_k(const float* __restrict__ in, const float* __restrict__ gw,
          const float* __restrict__ bw, float* __restrict__ outf,
          bf16* __restrict__ outb) {
  const int row = blockIdx.x, t = threadIdx.x;
  const float4 v = *(const float4*)(in + (size_t)row * DMODEL + t * 4);
  float s = v.x + v.y + v.z + v.w;
  float s2 = v.x * v.x + v.y * v.y + v.z * v.z + v.w * v.w;
  #pragma unroll
  for (int m = 1; m < 64; m <<= 1) { s += __shfl_xor(s, m); s2 += __shfl_xor(s2, m); }
  __shared__ float red[8];
  const int wid = t >> 6, lane = t & 63;
  if (lane == 0) { red[wid] = s; red[4 + wid] = s2; }
  __syncthreads();
  s = red[0] + red[1] + red[2] + red[3];
  s2 = red[4] + red[5] + red[6] + red[7];
  const float mu = s * (1.f / DMODEL);
  const float rstd = rsqrtf(s2 * (1.f / DMODEL) - mu * mu + 1e-5f);
  const float4 gv = *(const float4*)(gw + t * 4);
  const float4 bv = *(const float4*)(bw + t * 4);
  float o0 = (v.x - mu) * rstd * gv.x + bv.x;
  float o1 = (v.y - mu) * rstd * gv.y + bv.y;
  float o2 = (v.z - mu) * rstd * gv.z + bv.z;
  float o3 = (v.w - mu) * rstd * gv.w + bv.w;
  if (outf) {
    float4 ov = {o0, o1, o2, o3};
    *(float4*)(outf + (size_t)row * DMODEL + t * 4) = ov;
  }
  if (outb) {
    bf16* p = outb + (size_t)row * DMODEL + t * 4;
    p[0] = __float2bfloat16(o0); p[1] = __float2bfloat16(o1);
    p[2] = __float2bfloat16(o2); p[3] = __float2bfloat16(o3);
  }
}

extern "C" void kernel_launch(void* const* d_in, const int* in_sizes, int n_in,
                              void* d_out, int out_size, void* d_ws, size_t ws_size,
                              hipStream_t stream) {
  const float* x     = (const float*)d_in[0];
  const float* w_qkv = (const float*)d_in[1];
  const float* b_qkv = (const float*)d_in[2];
  const float* w_out = (const float*)d_in[3];
  const float* b_out = (const float*)d_in[4];
  const float* w_ff1 = (const float*)d_in[5];
  const float* b_ff1 = (const float*)d_in[6];
  const float* w_ff2 = (const float*)d_in[7];
  const float* b_ff2 = (const float*)d_in[8];
  const float* ln1_g = (const float*)d_in[9];
  const float* ln1_b = (const float*)d_in[10];
  const float* ln2_g = (const float*)d_in[11];
  const float* ln2_b = (const float*)d_in[12];
  float* out = (float*)d_out;

  // workspace layout (96 MiB; hb aliases the dead Q/K/Vt/xob pool)
  char* base = (char*)d_ws;
  bf16* wqkvT = (bf16*)(base);                 //  6291456 : 3072x1024
  bf16* woutT = (bf16*)(base + 6291456);       //  2097152 : 1024x1024
  bf16* wff1T = (bf16*)(base + 8388608);       //  8388608 : 4096x1024
  bf16* wff2T = (bf16*)(base + 16777216);      //  8388608 : 1024x4096
  bf16* Qb    = (bf16*)(base + 25165824);      //  8388608
  bf16* Kb    = (bf16*)(base + 33554432);      //  8388608
  bf16* Vtb   = (bf16*)(base + 41943040);      //  8388608
  bf16* xob   = (bf16*)(base + 50331648);      //  8388608 : x_bf16, later attn-out bf16
  bf16* hb    = (bf16*)(base + 25165824);      // 33554432 : aliases Qb..xob (dead by FF1)
  float* y    = (float*)(base + 58720256);     // 16777216 : y1 then y2
  float* x1f  = (float*)(base + 75497472);     // 16777216
  bf16* x1b   = (bf16*)(base + 92274688);      //  8388608
  (void)in_sizes; (void)n_in; (void)out_size; (void)ws_size;

  dim3 tb(32, 8);
  // prep: transpose weights to bf16 N x K, cast x to bf16
  transpose_cast_k<<<dim3(3072 / 32, 1024 / 32), tb, 0, stream>>>(w_qkv, wqkvT, 1024, 3072);
  transpose_cast_k<<<dim3(1024 / 32, 1024 / 32), tb, 0, stream>>>(w_out, woutT, 1024, 1024);
  transpose_cast_k<<<dim3(4096 / 32, 1024 / 32), tb, 0, stream>>>(w_ff1, wff1T, 1024, 4096);
  transpose_cast_k<<<dim3(1024 / 32, 4096 / 32), tb, 0, stream>>>(w_ff2, wff2T, 4096, 1024);
  cast_bf16_k<<<(TOKENS * DMODEL / 4 + 255) / 256, 256, 0, stream>>>(x, xob, TOKENS * DMODEL);

  // QKV projection + scatter
  gemm_bt<0><<<dim3(3072 / 128, TOKENS / 128), 256, 0, stream>>>(
      xob, wqkvT, b_qkv, TOKENS, 3072, 1024, nullptr, nullptr, nullptr, Qb, Kb, Vtb);
  // attention
  attn_k<<<dim3(32, 32), 256, 0, stream>>>(Qb, Kb, Vtb, xob);
  // out projection + residual (fp32 x)
  gemm_bt<1><<<dim3(1024 / 128, TOKENS / 128), 256, 0, stream>>>(
      xob, woutT, b_out, TOKENS, 1024, 1024, y, nullptr, x, nullptr, nullptr, nullptr);
  // LN1 -> x1 (fp32 + bf16)
  ln_k<<<TOKENS, 256, 0, stream>>>(y, ln1_g, ln1_b, x1f, x1b);
  // FF1 + GELU
  gemm_bt<2><<<dim3(4096 / 128, TOKENS / 128), 256, 0, stream>>>(
      x1b, wff1T, b_ff1, TOKENS, 4096, 1024, nullptr, hb, nullptr, nullptr, nullptr, nullptr);
  // FF2 + residual (fp32 x1)
  gemm_bt<1><<<dim3(1024 / 128, TOKENS / 128), 256, 0, stream>>>(
      hb, wff2T, b_ff2, TOKENS, 1024, 4096, y, nullptr, x1f, nullptr, nullptr, nullptr);
  // LN2 -> d_out
  ln_k<<<TOKENS, 256, 0, stream>>>(y, ln2_g, ln2_b, out, nullptr);
}

// Round 3
// 312.165 us; speedup vs baseline: 1.5141x; 1.5104x over previous
//
#include <hip/hip_runtime.h>
#include <hip/hip_bf16.h>
#include <cstdint>
#include <cstddef>

using bf16 = __hip_bfloat16;
typedef __attribute__((ext_vector_type(8))) short bf16x8;
typedef __attribute__((ext_vector_type(4))) float f32x4;

#define TOKENS 4096
#define DMODEL 1024
#define DFF    4096
#define SEQ    2048
#define NHEAD  16
#define HDIM   64
#define KVBLK  64
#define NT     (SEQ / KVBLK)

__device__ __forceinline__ void async16(const void* g, void* l) {
  __builtin_amdgcn_global_load_lds(
      (const __attribute__((address_space(1))) void*)g,
      (__attribute__((address_space(3))) void*)l, 16, 0, 0);
}

__device__ __forceinline__ f32x4 mfma16(bf16x8 a, bf16x8 b, f32x4 c) {
  return __builtin_amdgcn_mfma_f32_16x16x32_bf16(a, b, c, 0, 0, 0);
}

// ---------------- prep: fp32 -> bf16 cast ----------------
__global__ void cast_bf16_k(const float* __restrict__ src, bf16* __restrict__ dst, int n) {
  int i = (blockIdx.x * blockDim.x + threadIdx.x) * 4;
  if (i >= n) return;
  float4 v = *(const float4*)(src + i);
  dst[i + 0] = __float2bfloat16(v.x);
  dst[i + 1] = __float2bfloat16(v.y);
  dst[i + 2] = __float2bfloat16(v.z);
  dst[i + 3] = __float2bfloat16(v.w);
}

// ---------------- prep: fp32 KxN -> bf16 NxK transpose ----------------
__global__ void transpose_cast_k(const float* __restrict__ src, bf16* __restrict__ dst,
                                 int K, int N) {
  __shared__ float tile[32][33];
  int nt = blockIdx.x * 32, kt = blockIdx.y * 32;
  int tx = threadIdx.x, ty = threadIdx.y;   // block (32,8)
  #pragma unroll
  for (int i = 0; i < 32; i += 8)
    tile[ty + i][tx] = src[(size_t)(kt + ty + i) * N + nt + tx];
  __syncthreads();
  #pragma unroll
  for (int i = 0; i < 32; i += 8)
    dst[(size_t)(nt + ty + i) * K + kt + tx] = __float2bfloat16(tile[tx][ty + i]);
}

// ---------------- GEMM: C[M][N] = A[M][K] * Bt[N][K] + bias, fused epilogue ----------------
// EPI 0: QKV scatter to Q/K/Vt bf16.  EPI 1: fp32 out = v + resid.  EPI 2: bf16 out = gelu(v).
template <int EPI>
__global__ __launch_bounds__(256, 2)
void gemm_bt(const bf16* __restrict__ A, const bf16* __restrict__ Bt,
             const float* __restrict__ bias, int M, int N, int K,
             float* __restrict__ outf, bf16* __restrict__ outb,
             const float* __restrict__ resid,
             bf16* __restrict__ Qb, bf16* __restrict__ Kb, bf16* __restrict__ Vtb) {
  __shared__ bf16 Al[128 * 32];
  __shared__ bf16 Bl[128 * 32];
  const int t = threadIdx.x;
  // bijective XCD-chunked swizzle (all grids have nwg % 8 == 0)
  const int nwg = gridDim.x * gridDim.y;
  const int flat = blockIdx.y * gridDim.x + blockIdx.x;
  const int swz = (flat & 7) * (nwg >> 3) + (flat >> 3);
  const int bm = (swz / gridDim.x) * 128, bn = (swz % gridDim.x) * 128;
  const int wid = t >> 6, lane = t & 63, g = lane >> 4, r = lane & 15;
  const int wr = (wid >> 1) * 64, wc = (wid & 1) * 64;

  const f32x4 zero = {0.f, 0.f, 0.f, 0.f};
  f32x4 acc[4][4];
  #pragma unroll
  for (int i = 0; i < 4; i++)
    #pragma unroll
    for (int j = 0; j < 4; j++) acc[i][j] = zero;

  const int ch0 = t, ch1 = t + 256;
  const int r0 = ch0 >> 2, c0 = (ch0 & 3) * 8;
  const int r1 = ch1 >> 2, c1 = (ch1 & 3) * 8;

  #pragma unroll 1
  for (int kt = 0; kt < K; kt += 32) {
    async16(A + (size_t)(bm + r0) * K + kt + c0, (char*)Al + ch0 * 16);
    async16(A + (size_t)(bm + r1) * K + kt + c1, (char*)Al + ch1 * 16);
    async16(Bt + (size_t)(bn + r0) * K + kt + c0, (char*)Bl + ch0 * 16);
    async16(Bt + (size_t)(bn + r1) * K + kt + c1, (char*)Bl + ch1 * 16);
    __syncthreads();   // drains vmcnt before barrier
    bf16x8 af[4], bfr[4];
    #pragma unroll
    for (int mt = 0; mt < 4; mt++) af[mt] = *(const bf16x8*)&Al[(wr + mt * 16 + r) * 32 + 8 * g];
    #pragma unroll
    for (int nt = 0; nt < 4; nt++) bfr[nt] = *(const bf16x8*)&Bl[(wc + nt * 16 + r) * 32 + 8 * g];
    #pragma unroll
    for (int mt = 0; mt < 4; mt++)
      #pragma unroll
      for (int nt = 0; nt < 4; nt++)
        acc[mt][nt] = mfma16(af[mt], bfr[nt], acc[mt][nt]);
    __syncthreads();
  }

  // epilogue: row = bm+wr+mt*16+4g+j, col = bn+wc+nt*16+r
  #pragma unroll
  for (int nt = 0; nt < 4; nt++) {
    const int col = bn + wc + nt * 16 + r;
    const float bv = bias[col];
    #pragma unroll
    for (int mt = 0; mt < 4; mt++) {
      #pragma unroll
      for (int j = 0; j < 4; j++) {
        const int row = bm + wr + mt * 16 + 4 * g + j;
        float v = acc[mt][nt][j] + bv;
        if constexpr (EPI == 0) {
          const int part = col >> 10, hd = col & 1023, h = hd >> 6, d = hd & 63;
          const int b_ = row >> 11, s_ = row & 2047;
          const bf16 q = __float2bfloat16(v);
          if (part == 0)      Qb[((size_t)(b_ * NHEAD + h) * SEQ + s_) * HDIM + d] = q;
          else if (part == 1) Kb[((size_t)(b_ * NHEAD + h) * SEQ + s_) * HDIM + d] = q;
          else                Vtb[((size_t)(b_ * NHEAD + h) * HDIM + d) * SEQ + s_] = q;
        } else if constexpr (EPI == 1) {
          const size_t idx = (size_t)row * N + col;
          outf[idx] = v + resid[idx];
        } else {
          const size_t idx = (size_t)row * N + col;
          outb[idx] = __float2bfloat16(0.5f * v * (1.f + erff(v * 0.70710678118f)));
        }
      }
    }
  }
}

// ---------------- flash attention: LDS-staged, double-buffered, swizzled ----------------
// grid 1024 (XCD-chunked -> (bh,qb)), 256 thr = 4 waves, 16 q rows/wave, KVBLK=64.
// K/V tiles staged cooperatively via global_load_lds (linear dest, XOR-swizzled
// source; same XOR on ds_read — rule "both sides or neither").
// Pipeline: stage(t+1); s_waitcnt vmcnt(4); s_barrier; compute(t); s_barrier.
__global__ __launch_bounds__(256, 4)
void attn_k(const bf16* __restrict__ Q, const bf16* __restrict__ Km,
            const bf16* __restrict__ Vt, bf16* __restrict__ O) {
  __shared__ bf16 Kl[2][KVBLK * 64];   // [row][64 cols], 8 KB per buf
  __shared__ bf16 Vl[2][KVBLK * 64];   // [d-row][64 keys]
  __shared__ bf16 P[4][16 * 64];       // per-wave P, XOR-swizzled, 2 KB each
  const int b = blockIdx.x;
  const int bswz = (b & 7) * 128 + (b >> 3);        // XCD chunking: XCD gets 4 heads
  const int bh = bswz >> 5, qb = bswz & 31;
  const int t = threadIdx.x, wid = t >> 6, lane = t & 63, g = lane >> 4, r = lane & 15;
  const int q0 = qb * 64 + wid * 16;
  const bf16* Qp = Q + (size_t)bh * SEQ * HDIM;
  const char* Kc = (const char*)(Km + (size_t)bh * SEQ * HDIM);
  const char* Vc = (const char*)(Vt + (size_t)bh * HDIM * SEQ);

  // Q B-fragments (registers for the whole kernel)
  const bf16x8 qf0 = *(const bf16x8*)&Qp[(q0 + r) * HDIM + 8 * g];
  const bf16x8 qf1 = *(const bf16x8*)&Qp[(q0 + r) * HDIM + 8 * g + 32];

  // staging offsets: this thread covers two 16B lanesx16 chunks of each 8KB tile
  const int o0 = wid * 2048 + lane * 16, o1 = o0 + 1024;
  // XOR swizzle of the 16B column slot by row&7
  const int cs0 = ((((o0 >> 4) & 7) ^ ((o0 >> 7) & 7)) << 4);
  const int cs1 = ((((o1 >> 4) & 7) ^ ((o1 >> 7) & 7)) << 4);
  const int kso0 = (o0 & ~127) + cs0, kso1 = (o1 & ~127) + cs1;        // K: rows contiguous
  const int vso0 = (o0 >> 7) * (SEQ * 2) + cs0, vso1 = (o1 >> 7) * (SEQ * 2) + cs1;

  const f32x4 zero = {0.f, 0.f, 0.f, 0.f};
  f32x4 oacc[4];
  #pragma unroll
  for (int i = 0; i < 4; i++) oacc[i] = zero;
  float mrow = -1e30f, lrow = 0.f;
  bf16* pl = P[wid];
  // per-lane swizzled column slots (bf16 units): c0 for cols 0..31, c1 for 32..63
  const int cA = ((g ^ (r & 7)) << 3), cB = (((g + 4) ^ (r & 7)) << 3);

  // prologue: stage tile 0
  {
    const char* ks = Kc; const char* vs = Vc;
    char* kd = (char*)Kl[0]; char* vd = (char*)Vl[0];
    async16(ks + kso0, kd + o0); async16(ks + kso1, kd + o1);
    async16(vs + vso0, vd + o0); async16(vs + vso1, vd + o1);
  }

  #pragma unroll 1
  for (int tt = 0; tt < NT; ++tt) {
    if (tt + 1 < NT) {
      const char* ks = Kc + (tt + 1) * (KVBLK * HDIM * 2);   // 8KB contiguous K tile
      const char* vs = Vc + (tt + 1) * (KVBLK * 2);          // 128B col offset in V
      char* kd = (char*)Kl[(tt + 1) & 1]; char* vd = (char*)Vl[(tt + 1) & 1];
      async16(ks + kso0, kd + o0); async16(ks + kso1, kd + o1);
      async16(vs + vso0, vd + o0); async16(vs + vso1, vd + o1);
      asm volatile("s_waitcnt vmcnt(4)" ::: "memory");   // tile tt landed, tt+1 in flight
    } else {
      asm volatile("s_waitcnt vmcnt(0)" ::: "memory");
    }
    __builtin_amdgcn_sched_barrier(0);
    __builtin_amdgcn_s_barrier();
    __builtin_amdgcn_sched_barrier(0);

    const bf16* kbuf = Kl[tt & 1];
    const bf16* vbuf = Vl[tt & 1];

    // ---- QK^T (swapped): A = K rows from LDS, B = Q ----
    f32x4 sacc[4];
    #pragma unroll
    for (int kt = 0; kt < 4; kt++) {
      const bf16* krow = kbuf + (kt * 16 + r) * 64;
      bf16x8 ka = *(const bf16x8*)&krow[cA];
      bf16x8 kb = *(const bf16x8*)&krow[cB];
      f32x4 s = zero;
      s = mfma16(ka, qf0, s);
      s = mfma16(kb, qf1, s);
      sacc[kt] = s;
    }

    // ---- softmax: 16 per-lane values of one q-row (q = r) ----
    float sv[4][4];
    #pragma unroll
    for (int kt = 0; kt < 4; kt++)
      #pragma unroll
      for (int j = 0; j < 4; j++) sv[kt][j] = sacc[kt][j] * 0.125f;
    float m0 = fmaxf(fmaxf(sv[0][0], sv[0][1]), fmaxf(sv[0][2], sv[0][3]));
    float m1 = fmaxf(fmaxf(sv[1][0], sv[1][1]), fmaxf(sv[1][2], sv[1][3]));
    float m2 = fmaxf(fmaxf(sv[2][0], sv[2][1]), fmaxf(sv[2][2], sv[2][3]));
    float m3 = fmaxf(fmaxf(sv[3][0], sv[3][1]), fmaxf(sv[3][2], sv[3][3]));
    float mx = fmaxf(fmaxf(m0, m1), fmaxf(m2, m3));
    mx = fmaxf(mx, __shfl_xor(mx, 16));
    mx = fmaxf(mx, __shfl_xor(mx, 32));
    const float mn = fmaxf(mrow, mx);
    const float corr = __expf(mrow - mn);
    mrow = mn;
    float sum = 0.f;
    #pragma unroll
    for (int kt = 0; kt < 4; kt++)
      #pragma unroll
      for (int j = 0; j < 4; j++) {
        const float p = __expf(sv[kt][j] - mn);
        sv[kt][j] = p;
        sum += p;
      }
    sum += __shfl_xor(sum, 16);
    sum += __shfl_xor(sum, 32);
    lrow = lrow * corr + sum;

    // ---- P -> per-wave LDS (swizzled), read back as PV A-fragments ----
    #pragma unroll
    for (int kt = 0; kt < 4; kt++) {
      bf16 pk[4] = {__float2bfloat16(sv[kt][0]), __float2bfloat16(sv[kt][1]),
                    __float2bfloat16(sv[kt][2]), __float2bfloat16(sv[kt][3])};
      const int pc = (((kt * 2 + (g >> 1)) ^ (r & 7)) << 4) + ((g & 1) << 3);
      *(short4*)((char*)pl + r * 128 + pc) = *(const short4*)pk;
    }
    asm volatile("s_waitcnt lgkmcnt(0)" ::: "memory");
    __builtin_amdgcn_sched_barrier(0);
    const bf16x8 pf0 = *(const bf16x8*)((const char*)pl + r * 128 + (cA << 1));
    const bf16x8 pf1 = *(const bf16x8*)((const char*)pl + r * 128 + (cB << 1));

    // corr for this lane's O rows (q_local = 4g+j lives at lane 4g+j)
    float cq[4];
    #pragma unroll
    for (int j = 0; j < 4; j++) cq[j] = __shfl(corr, 4 * g + j);

    // ---- PV: A = P rows (q), B = V^T rows (d) from LDS ----
    #pragma unroll
    for (int dt = 0; dt < 4; dt++) {
      const bf16* vrow = vbuf + (dt * 16 + r) * 64;
      bf16x8 v0 = *(const bf16x8*)&vrow[cA];
      bf16x8 v1 = *(const bf16x8*)&vrow[cB];
      #pragma unroll
      for (int j = 0; j < 4; j++) oacc[dt][j] *= cq[j];
      oacc[dt] = mfma16(pf0, v0, oacc[dt]);
      oacc[dt] = mfma16(pf1, v1, oacc[dt]);
    }
    __builtin_amdgcn_sched_barrier(0);
    __builtin_amdgcn_s_barrier();   // reads of buf tt done before stage(tt+2) overwrites
  }

  float lq[4];
  #pragma unroll
  for (int j = 0; j < 4; j++) lq[j] = __shfl(lrow, 4 * g + j);
  const int b_ = bh >> 4, h = bh & 15;
  #pragma unroll
  for (int dt = 0; dt < 4; dt++)
    #pragma unroll
    for (int j = 0; j < 4; j++) {
      const int tok = b_ * SEQ + q0 + 4 * g + j;
      O[(size_t)tok * DMODEL + h * HDIM + dt * 16 + r] =
          __float2bfloat16(oacc[dt][j] / lq[j]);
    }
}

// ---------------- LayerNorm (one block per row of 1024) ----------------
__global__ __launch_bounds__(256)
void ln_k(const float* __restrict__ in, const float* __restrict__ gw,
          const float* __restrict__ bw, float* __restrict__ outf,
          bf16* __restrict__ outb) {
  const int row = blockIdx.x, t = threadIdx.x;
  const float4 v = *(const float4*)(in + (size_t)row * DMODEL + t * 4);
  float s = v.x + v.y + v.z + v.w;
  float s2 = v.x * v.x + v.y * v.y + v.z * v.z + v.w * v.w;
  #pragma unroll
  for (int m = 1; m < 64; m <<= 1) { s += __shfl_xor(s, m); s2 += __shfl_xor(s2, m); }
  __shared__ float red[8];
  const int wid = t >> 6, lane = t & 63;
  if (lane == 0) { red[wid] = s; red[4 + wid] = s2; }
  __syncthreads();
  s = red[0] + red[1] + red[2] + red[3];
  s2 = red[4] + red[5] + red[6] + red[7];
  const float mu = s * (1.f / DMODEL);
  const float rstd = rsqrtf(s2 * (1.f / DMODEL) - mu * mu + 1e-5f);
  const float4 gv = *(const float4*)(gw + t * 4);
  const float4 bv = *(const float4*)(bw + t * 4);
  float o0 = (v.x - mu) * rstd * gv.x + bv.x;
  float o1 = (v.y - mu) * rstd * gv.y + bv.y;
  float o2 = (v.z - mu) * rstd * gv.z + bv.z;
  float o3 = (v.w - mu) * rstd * gv.w + bv.w;
  if (outf) {
    float4 ov = {o0, o1, o2, o3};
    *(float4*)(outf + (size_t)row * DMODEL + t * 4) = ov;
  }
  if (outb) {
    bf16* p = outb + (size_t)row * DMODEL + t * 4;
    p[0] = __float2bfloat16(o0); p[1] = __float2bfloat16(o1);
    p[2] = __float2bfloat16(o2); p[3] = __float2bfloat16(o3);
  }
}

extern "C" void kernel_launch(void* const* d_in, const int* in_sizes, int n_in,
                              void* d_out, int out_size, void* d_ws, size_t ws_size,
                              hipStream_t stream) {
  const float* x     = (const float*)d_in[0];
  const float* w_qkv = (const float*)d_in[1];
  const float* b_qkv = (const float*)d_in[2];
  const float* w_out = (const float*)d_in[3];
  const float* b_out = (const float*)d_in[4];
  const float* w_ff1 = (const float*)d_in[5];
  const float* b_ff1 = (const float*)d_in[6];
  const float* w_ff2 = (const float*)d_in[7];
  const float* b_ff2 = (const float*)d_in[8];
  const float* ln1_g = (const float*)d_in[9];
  const float* ln1_b = (const float*)d_in[10];
  const float* ln2_g = (const float*)d_in[11];
  const float* ln2_b = (const float*)d_in[12];
  float* out = (float*)d_out;

  // workspace layout (96 MiB; hb aliases the dead Q/K/Vt/xob pool)
  char* base = (char*)d_ws;
  bf16* wqkvT = (bf16*)(base);                 //  6291456 : 3072x1024
  bf16* woutT = (bf16*)(base + 6291456);       //  2097152 : 1024x1024
  bf16* wff1T = (bf16*)(base + 8388608);       //  8388608 : 4096x1024
  bf16* wff2T = (bf16*)(base + 16777216);      //  8388608 : 1024x4096
  bf16* Qb    = (bf16*)(base + 25165824);      //  8388608
  bf16* Kb    = (bf16*)(base + 33554432);      //  8388608
  bf16* Vtb   = (bf16*)(base + 41943040);      //  8388608
  bf16* xob   = (bf16*)(base + 50331648);      //  8388608 : x_bf16, later attn-out bf16
  bf16* hb    = (bf16*)(base + 25165824);      // 33554432 : aliases Qb..xob (dead by FF1)
  float* y    = (float*)(base + 58720256);     // 16777216 : y1 then y2
  float* x1f  = (float*)(base + 75497472);     // 16777216
  bf16* x1b   = (bf16*)(base + 92274688);      //  8388608
  (void)in_sizes; (void)n_in; (void)out_size; (void)ws_size;

  dim3 tb(32, 8);
  // prep: transpose weights to bf16 N x K, cast x to bf16
  transpose_cast_k<<<dim3(3072 / 32, 1024 / 32), tb, 0, stream>>>(w_qkv, wqkvT, 1024, 3072);
  transpose_cast_k<<<dim3(1024 / 32, 1024 / 32), tb, 0, stream>>>(w_out, woutT, 1024, 1024);
  transpose_cast_k<<<dim3(4096 / 32, 1024 / 32), tb, 0, stream>>>(w_ff1, wff1T, 1024, 4096);
  transpose_cast_k<<<dim3(1024 / 32, 4096 / 32), tb, 0, stream>>>(w_ff2, wff2T, 4096, 1024);
  cast_bf16_k<<<(TOKENS * DMODEL / 4 + 255) / 256, 256, 0, stream>>>(x, xob, TOKENS * DMODEL);

  // QKV projection + scatter
  gemm_bt<0><<<dim3(3072 / 128, TOKENS / 128), 256, 0, stream>>>(
      xob, wqkvT, b_qkv, TOKENS, 3072, 1024, nullptr, nullptr, nullptr, Qb, Kb, Vtb);
  // attention
  attn_k<<<dim3(1024), 256, 0, stream>>>(Qb, Kb, Vtb, xob);
  // out projection + residual (fp32 x)
  gemm_bt<1><<<dim3(1024 / 128, TOKENS / 128), 256, 0, stream>>>(
      xob, woutT, b_out, TOKENS, 1024, 1024, y, nullptr, x, nullptr, nullptr, nullptr);
  // LN1 -> x1 (fp32 + bf16)
  ln_k<<<TOKENS, 256, 0, stream>>>(y, ln1_g, ln1_b, x1f, x1b);
  // FF1 + GELU
  gemm_bt<2><<<dim3(4096 / 128, TOKENS / 128), 256, 0, stream>>>(
      x1b, wff1T, b_ff1, TOKENS, 4096, 1024, nullptr, hb, nullptr, nullptr, nullptr, nullptr);
  // FF2 + residual (fp32 x1)
  gemm_bt<1><<<dim3(1024 / 128, TOKENS / 128), 256, 0, stream>>>(
      hb, wff2T, b_ff2, TOKENS, 1024, 4096, y, nullptr, x1f, nullptr, nullptr, nullptr);
  // LN2 -> d_out
  ln_k<<<TOKENS, 256, 0, stream>>>(y, ln2_g, ln2_b, out, nullptr);
}

// Round 4
// 290.670 us; speedup vs baseline: 1.6260x; 1.0740x over previous
//
#include <hip/hip_runtime.h>
#include <hip/hip_bf16.h>
#include <cstdint>
#include <cstddef>

using bf16 = __hip_bfloat16;
typedef __attribute__((ext_vector_type(8))) short bf16x8;
typedef __attribute__((ext_vector_type(4))) float f32x4;

#define TOKENS 4096
#define DMODEL 1024
#define DFF    4096
#define SEQ    2048
#define NHEAD  16
#define HDIM   64
#define KVBLK  64
#define NT     (SEQ / KVBLK)

__device__ __forceinline__ void async16(const void* g, void* l) {
  __builtin_amdgcn_global_load_lds(
      (const __attribute__((address_space(1))) void*)g,
      (__attribute__((address_space(3))) void*)l, 16, 0, 0);
}

__device__ __forceinline__ f32x4 mfma16(bf16x8 a, bf16x8 b, f32x4 c) {
  return __builtin_amdgcn_mfma_f32_16x16x32_bf16(a, b, c, 0, 0, 0);
}

// ---------------- prep: fp32 -> bf16 cast ----------------
__global__ void cast_bf16_k(const float* __restrict__ src, bf16* __restrict__ dst, int n) {
  int i = (blockIdx.x * blockDim.x + threadIdx.x) * 4;
  if (i >= n) return;
  float4 v = *(const float4*)(src + i);
  dst[i + 0] = __float2bfloat16(v.x);
  dst[i + 1] = __float2bfloat16(v.y);
  dst[i + 2] = __float2bfloat16(v.z);
  dst[i + 3] = __float2bfloat16(v.w);
}

// ---------------- prep: fp32 KxN -> bf16 NxK transpose ----------------
__global__ void transpose_cast_k(const float* __restrict__ src, bf16* __restrict__ dst,
                                 int K, int N) {
  __shared__ float tile[32][33];
  int nt = blockIdx.x * 32, kt = blockIdx.y * 32;
  int tx = threadIdx.x, ty = threadIdx.y;   // block (32,8)
  #pragma unroll
  for (int i = 0; i < 32; i += 8)
    tile[ty + i][tx] = src[(size_t)(kt + ty + i) * N + nt + tx];
  __syncthreads();
  #pragma unroll
  for (int i = 0; i < 32; i += 8)
    dst[(size_t)(nt + ty + i) * K + kt + tx] = __float2bfloat16(tile[tx][ty + i]);
}

// ---------------- GEMM: C[M][N] = A[M][K] * Bt[N][K] + bias, fused epilogue ----------------
// 2-phase pipelined (double-buffered LDS, stage(t+1) before compute(t), one
// vmcnt(0)+s_barrier per K-tile). BM=128 always; BN=128 (waves 2x2, acc 4x4)
// or BN=64 (waves 4x1, acc 2x4) for N=1024 GEMMs to double the grid.
// EPI 0: QKV scatter to Q/K/Vt bf16.  EPI 1: fp32 out = v + resid.  EPI 2: bf16 out = gelu(v).
template <int EPI, int BN>
__global__ __launch_bounds__(256, 2)
void gemm_bt(const bf16* __restrict__ A, const bf16* __restrict__ Bt,
             const float* __restrict__ bias, int M, int N, int K,
             float* __restrict__ outf, bf16* __restrict__ outb,
             const float* __restrict__ resid,
             bf16* __restrict__ Qb, bf16* __restrict__ Kb, bf16* __restrict__ Vtb) {
  constexpr int MR = (BN == 128) ? 4 : 2;     // 16-row frags per wave in M
  __shared__ bf16 Al[2][128 * 32];
  __shared__ bf16 Bl[2][BN * 32];
  const int t = threadIdx.x;
  // bijective XCD-chunked swizzle (all grids have nwg % 8 == 0)
  const int nwg = gridDim.x * gridDim.y;
  const int flat = blockIdx.y * gridDim.x + blockIdx.x;
  const int swz = (flat & 7) * (nwg >> 3) + (flat >> 3);
  const int bm = (swz / gridDim.x) * 128, bn = (swz % gridDim.x) * BN;
  const int wid = t >> 6, lane = t & 63, g = lane >> 4, r = lane & 15;
  const int wr = (BN == 128) ? (wid >> 1) * 64 : wid * 32;
  const int wc = (BN == 128) ? (wid & 1) * 64 : 0;

  const f32x4 zero = {0.f, 0.f, 0.f, 0.f};
  f32x4 acc[MR][4];
  #pragma unroll
  for (int i = 0; i < MR; i++)
    #pragma unroll
    for (int j = 0; j < 4; j++) acc[i][j] = zero;

  // staging coords: chunk ch covers row ch>>2, 8-col group (ch&3)*8 of a [rows][32] tile
  const int ar0 = t >> 2, ac = (t & 3) * 8;
  const int ar1 = ar0 + 64;
  const int ach0 = t * 16, ach1 = ach0 + 4096;

  const int NK = K >> 5;
  #define STAGE(ktile, pb)                                                          \
    do {                                                                            \
      const int kk = (ktile) << 5;                                                  \
      async16(A + (size_t)(bm + ar0) * K + kk + ac, (char*)Al[pb] + ach0);          \
      async16(A + (size_t)(bm + ar1) * K + kk + ac, (char*)Al[pb] + ach1);          \
      async16(Bt + (size_t)(bn + ar0) * K + kk + ac, (char*)Bl[pb] + ach0);         \
      if constexpr (BN == 128)                                                      \
        async16(Bt + (size_t)(bn + ar1) * K + kk + ac, (char*)Bl[pb] + ach1);       \
    } while (0)

  STAGE(0, 0);
  asm volatile("s_waitcnt vmcnt(0)" ::: "memory");
  __builtin_amdgcn_s_barrier();

  #pragma unroll 1
  for (int it = 0; it < NK; ++it) {
    const int cur = it & 1;
    if (it + 1 < NK) STAGE(it + 1, cur ^ 1);
    bf16x8 af[MR], bfr[4];
    #pragma unroll
    for (int mt = 0; mt < MR; mt++)
      af[mt] = *(const bf16x8*)&Al[cur][(wr + mt * 16 + r) * 32 + 8 * g];
    #pragma unroll
    for (int nt = 0; nt < 4; nt++)
      bfr[nt] = *(const bf16x8*)&Bl[cur][(wc + nt * 16 + r) * 32 + 8 * g];
    #pragma unroll
    for (int mt = 0; mt < MR; mt++)
      #pragma unroll
      for (int nt = 0; nt < 4; nt++)
        acc[mt][nt] = mfma16(af[mt], bfr[nt], acc[mt][nt]);
    __builtin_amdgcn_sched_barrier(0);
    asm volatile("s_waitcnt vmcnt(0)" ::: "memory");
    __builtin_amdgcn_s_barrier();
  }
  #undef STAGE

  // epilogue: row = bm+wr+mt*16+4g+j, col = bn+wc+nt*16+r
  #pragma unroll
  for (int nt = 0; nt < 4; nt++) {
    const int col = bn + wc + nt * 16 + r;
    const float bv = bias[col];
    #pragma unroll
    for (int mt = 0; mt < MR; mt++) {
      #pragma unroll
      for (int j = 0; j < 4; j++) {
        const int row = bm + wr + mt * 16 + 4 * g + j;
        float v = acc[mt][nt][j] + bv;
        if constexpr (EPI == 0) {
          const int part = col >> 10, hd = col & 1023, h = hd >> 6, d = hd & 63;
          const int b_ = row >> 11, s_ = row & 2047;
          const bf16 q = __float2bfloat16(v);
          if (part == 0)      Qb[((size_t)(b_ * NHEAD + h) * SEQ + s_) * HDIM + d] = q;
          else if (part == 1) Kb[((size_t)(b_ * NHEAD + h) * SEQ + s_) * HDIM + d] = q;
          else                Vtb[((size_t)(b_ * NHEAD + h) * HDIM + d) * SEQ + s_] = q;
        } else if constexpr (EPI == 1) {
          const size_t idx = (size_t)row * N + col;
          outf[idx] = v + resid[idx];
        } else {
          const size_t idx = (size_t)row * N + col;
          outb[idx] = __float2bfloat16(0.5f * v * (1.f + erff(v * 0.70710678118f)));
        }
      }
    }
  }
}

// ---------------- flash attention: LDS-staged, double-buffered, swizzled ----------------
// grid 1024 (XCD-chunked -> (bh,qb)), 256 thr = 4 waves, 16 q rows/wave, KVBLK=64.
__global__ __launch_bounds__(256, 4)
void attn_k(const bf16* __restrict__ Q, const bf16* __restrict__ Km,
            const bf16* __restrict__ Vt, bf16* __restrict__ O) {
  __shared__ bf16 Kl[2][KVBLK * 64];   // [row][64 cols], 8 KB per buf
  __shared__ bf16 Vl[2][KVBLK * 64];   // [d-row][64 keys]
  __shared__ bf16 P[4][16 * 64];       // per-wave P, XOR-swizzled, 2 KB each
  const int b = blockIdx.x;
  const int bswz = (b & 7) * 128 + (b >> 3);        // XCD chunking: XCD gets 4 heads
  const int bh = bswz >> 5, qb = bswz & 31;
  const int t = threadIdx.x, wid = t >> 6, lane = t & 63, g = lane >> 4, r = lane & 15;
  const int q0 = qb * 64 + wid * 16;
  const bf16* Qp = Q + (size_t)bh * SEQ * HDIM;
  const char* Kc = (const char*)(Km + (size_t)bh * SEQ * HDIM);
  const char* Vc = (const char*)(Vt + (size_t)bh * HDIM * SEQ);

  const bf16x8 qf0 = *(const bf16x8*)&Qp[(q0 + r) * HDIM + 8 * g];
  const bf16x8 qf1 = *(const bf16x8*)&Qp[(q0 + r) * HDIM + 8 * g + 32];

  const int o0 = wid * 2048 + lane * 16, o1 = o0 + 1024;
  const int cs0 = ((((o0 >> 4) & 7) ^ ((o0 >> 7) & 7)) << 4);
  const int cs1 = ((((o1 >> 4) & 7) ^ ((o1 >> 7) & 7)) << 4);
  const int kso0 = (o0 & ~127) + cs0, kso1 = (o1 & ~127) + cs1;
  const int vso0 = (o0 >> 7) * (SEQ * 2) + cs0, vso1 = (o1 >> 7) * (SEQ * 2) + cs1;

  const f32x4 zero = {0.f, 0.f, 0.f, 0.f};
  f32x4 oacc[4];
  #pragma unroll
  for (int i = 0; i < 4; i++) oacc[i] = zero;
  float mrow = -1e30f, lrow = 0.f;
  bf16* pl = P[wid];
  const int cA = ((g ^ (r & 7)) << 3), cB = (((g + 4) ^ (r & 7)) << 3);

  {
    const char* ks = Kc; const char* vs = Vc;
    char* kd = (char*)Kl[0]; char* vd = (char*)Vl[0];
    async16(ks + kso0, kd + o0); async16(ks + kso1, kd + o1);
    async16(vs + vso0, vd + o0); async16(vs + vso1, vd + o1);
  }

  #pragma unroll 1
  for (int tt = 0; tt < NT; ++tt) {
    if (tt + 1 < NT) {
      const char* ks = Kc + (tt + 1) * (KVBLK * HDIM * 2);
      const char* vs = Vc + (tt + 1) * (KVBLK * 2);
      char* kd = (char*)Kl[(tt + 1) & 1]; char* vd = (char*)Vl[(tt + 1) & 1];
      async16(ks + kso0, kd + o0); async16(ks + kso1, kd + o1);
      async16(vs + vso0, vd + o0); async16(vs + vso1, vd + o1);
      asm volatile("s_waitcnt vmcnt(4)" ::: "memory");
    } else {
      asm volatile("s_waitcnt vmcnt(0)" ::: "memory");
    }
    __builtin_amdgcn_sched_barrier(0);
    __builtin_amdgcn_s_barrier();
    __builtin_amdgcn_sched_barrier(0);

    const bf16* kbuf = Kl[tt & 1];
    const bf16* vbuf = Vl[tt & 1];

    f32x4 sacc[4];
    #pragma unroll
    for (int kt = 0; kt < 4; kt++) {
      const bf16* krow = kbuf + (kt * 16 + r) * 64;
      bf16x8 ka = *(const bf16x8*)&krow[cA];
      bf16x8 kb = *(const bf16x8*)&krow[cB];
      f32x4 s = zero;
      s = mfma16(ka, qf0, s);
      s = mfma16(kb, qf1, s);
      sacc[kt] = s;
    }

    float sv[4][4];
    #pragma unroll
    for (int kt = 0; kt < 4; kt++)
      #pragma unroll
      for (int j = 0; j < 4; j++) sv[kt][j] = sacc[kt][j] * 0.125f;
    float m0 = fmaxf(fmaxf(sv[0][0], sv[0][1]), fmaxf(sv[0][2], sv[0][3]));
    float m1 = fmaxf(fmaxf(sv[1][0], sv[1][1]), fmaxf(sv[1][2], sv[1][3]));
    float m2 = fmaxf(fmaxf(sv[2][0], sv[2][1]), fmaxf(sv[2][2], sv[2][3]));
    float m3 = fmaxf(fmaxf(sv[3][0], sv[3][1]), fmaxf(sv[3][2], sv[3][3]));
    float mx = fmaxf(fmaxf(m0, m1), fmaxf(m2, m3));
    mx = fmaxf(mx, __shfl_xor(mx, 16));
    mx = fmaxf(mx, __shfl_xor(mx, 32));
    const float mn = fmaxf(mrow, mx);
    const float corr = __expf(mrow - mn);
    mrow = mn;
    float sum = 0.f;
    #pragma unroll
    for (int kt = 0; kt < 4; kt++)
      #pragma unroll
      for (int j = 0; j < 4; j++) {
        const float p = __expf(sv[kt][j] - mn);
        sv[kt][j] = p;
        sum += p;
      }
    sum += __shfl_xor(sum, 16);
    sum += __shfl_xor(sum, 32);
    lrow = lrow * corr + sum;

    #pragma unroll
    for (int kt = 0; kt < 4; kt++) {
      bf16 pk[4] = {__float2bfloat16(sv[kt][0]), __float2bfloat16(sv[kt][1]),
                    __float2bfloat16(sv[kt][2]), __float2bfloat16(sv[kt][3])};
      const int pc = (((kt * 2 + (g >> 1)) ^ (r & 7)) << 4) + ((g & 1) << 3);
      *(short4*)((char*)pl + r * 128 + pc) = *(const short4*)pk;
    }
    asm volatile("s_waitcnt lgkmcnt(0)" ::: "memory");
    __builtin_amdgcn_sched_barrier(0);
    const bf16x8 pf0 = *(const bf16x8*)((const char*)pl + r * 128 + (cA << 1));
    const bf16x8 pf1 = *(const bf16x8*)((const char*)pl + r * 128 + (cB << 1));

    float cq[4];
    #pragma unroll
    for (int j = 0; j < 4; j++) cq[j] = __shfl(corr, 4 * g + j);

    #pragma unroll
    for (int dt = 0; dt < 4; dt++) {
      const bf16* vrow = vbuf + (dt * 16 + r) * 64;
      bf16x8 v0 = *(const bf16x8*)&vrow[cA];
      bf16x8 v1 = *(const bf16x8*)&vrow[cB];
      #pragma unroll
      for (int j = 0; j < 4; j++) oacc[dt][j] *= cq[j];
      oacc[dt] = mfma16(pf0, v0, oacc[dt]);
      oacc[dt] = mfma16(pf1, v1, oacc[dt]);
    }
    __builtin_amdgcn_sched_barrier(0);
    __builtin_amdgcn_s_barrier();
  }

  float lq[4];
  #pragma unroll
  for (int j = 0; j < 4; j++) lq[j] = __shfl(lrow, 4 * g + j);
  const int b_ = bh >> 4, h = bh & 15;
  #pragma unroll
  for (int dt = 0; dt < 4; dt++)
    #pragma unroll
    for (int j = 0; j < 4; j++) {
      const int tok = b_ * SEQ + q0 + 4 * g + j;
      O[(size_t)tok * DMODEL + h * HDIM + dt * 16 + r] =
          __float2bfloat16(oacc[dt][j] / lq[j]);
    }
}

// ---------------- LayerNorm (one block per row of 1024) ----------------
__global__ __launch_bounds__(256)
void ln_k(const float* __restrict__ in, const float* __restrict__ gw,
          const float* __restrict__ bw, float* __restrict__ outf,
          bf16* __restrict__ outb) {
  const int row = blockIdx.x, t = threadIdx.x;
  const float4 v = *(const float4*)(in + (size_t)row * DMODEL + t * 4);
  float s = v.x + v.y + v.z + v.w;
  float s2 = v.x * v.x + v.y * v.y + v.z * v.z + v.w * v.w;
  #pragma unroll
  for (int m = 1; m < 64; m <<= 1) { s += __shfl_xor(s, m); s2 += __shfl_xor(s2, m); }
  __shared__ float red[8];
  const int wid = t >> 6, lane = t & 63;
  if (lane == 0) { red[wid] = s; red[4 + wid] = s2; }
  __syncthreads();
  s = red[0] + red[1] + red[2] + red[3];
  s2 = red[4] + red[5] + red[6] + red[7];
  const float mu = s * (1.f / DMODEL);
  const float rstd = rsqrtf(s2 * (1.f / DMODEL) - mu * mu + 1e-5f);
  const float4 gv = *(const float4*)(gw + t * 4);
  const float4 bv = *(const float4*)(bw + t * 4);
  float o0 = (v.x - mu) * rstd * gv.x + bv.x;
  float o1 = (v.y - mu) * rstd * gv.y + bv.y;
  float o2 = (v.z - mu) * rstd * gv.z + bv.z;
  float o3 = (v.w - mu) * rstd * gv.w + bv.w;
  if (outf) {
    float4 ov = {o0, o1, o2, o3};
    *(float4*)(outf + (size_t)row * DMODEL + t * 4) = ov;
  }
  if (outb) {
    bf16* p = outb + (size_t)row * DMODEL + t * 4;
    p[0] = __float2bfloat16(o0); p[1] = __float2bfloat16(o1);
    p[2] = __float2bfloat16(o2); p[3] = __float2bfloat16(o3);
  }
}

extern "C" void kernel_launch(void* const* d_in, const int* in_sizes, int n_in,
                              void* d_out, int out_size, void* d_ws, size_t ws_size,
                              hipStream_t stream) {
  const float* x     = (const float*)d_in[0];
  const float* w_qkv = (const float*)d_in[1];
  const float* b_qkv = (const float*)d_in[2];
  const float* w_out = (const float*)d_in[3];
  const float* b_out = (const float*)d_in[4];
  const float* w_ff1 = (const float*)d_in[5];
  const float* b_ff1 = (const float*)d_in[6];
  const float* w_ff2 = (const float*)d_in[7];
  const float* b_ff2 = (const float*)d_in[8];
  const float* ln1_g = (const float*)d_in[9];
  const float* ln1_b = (const float*)d_in[10];
  const float* ln2_g = (const float*)d_in[11];
  const float* ln2_b = (const float*)d_in[12];
  float* out = (float*)d_out;

  // workspace layout (96 MiB; hb aliases the dead Q/K/Vt/xob pool)
  char* base = (char*)d_ws;
  bf16* wqkvT = (bf16*)(base);                 //  6291456 : 3072x1024
  bf16* woutT = (bf16*)(base + 6291456);       //  2097152 : 1024x1024
  bf16* wff1T = (bf16*)(base + 8388608);       //  8388608 : 4096x1024
  bf16* wff2T = (bf16*)(base + 16777216);      //  8388608 : 1024x4096
  bf16* Qb    = (bf16*)(base + 25165824);      //  8388608
  bf16* Kb    = (bf16*)(base + 33554432);      //  8388608
  bf16* Vtb   = (bf16*)(base + 41943040);      //  8388608
  bf16* xob   = (bf16*)(base + 50331648);      //  8388608 : x_bf16, later attn-out bf16
  bf16* hb    = (bf16*)(base + 25165824);      // 33554432 : aliases Qb..xob (dead by FF1)
  float* y    = (float*)(base + 58720256);     // 16777216 : y1 then y2
  float* x1f  = (float*)(base + 75497472);     // 16777216
  bf16* x1b   = (bf16*)(base + 92274688);      //  8388608
  (void)in_sizes; (void)n_in; (void)out_size; (void)ws_size;

  dim3 tb(32, 8);
  // prep: transpose weights to bf16 N x K, cast x to bf16
  transpose_cast_k<<<dim3(3072 / 32, 1024 / 32), tb, 0, stream>>>(w_qkv, wqkvT, 1024, 3072);
  transpose_cast_k<<<dim3(1024 / 32, 1024 / 32), tb, 0, stream>>>(w_out, woutT, 1024, 1024);
  transpose_cast_k<<<dim3(4096 / 32, 1024 / 32), tb, 0, stream>>>(w_ff1, wff1T, 1024, 4096);
  transpose_cast_k<<<dim3(1024 / 32, 4096 / 32), tb, 0, stream>>>(w_ff2, wff2T, 4096, 1024);
  cast_bf16_k<<<(TOKENS * DMODEL / 4 + 255) / 256, 256, 0, stream>>>(x, xob, TOKENS * DMODEL);

  // QKV projection + scatter
  gemm_bt<0, 128><<<dim3(3072 / 128, TOKENS / 128), 256, 0, stream>>>(
      xob, wqkvT, b_qkv, TOKENS, 3072, 1024, nullptr, nullptr, nullptr, Qb, Kb, Vtb);
  // attention
  attn_k<<<dim3(1024), 256, 0, stream>>>(Qb, Kb, Vtb, xob);
  // out projection + residual (fp32 x)  — BN=64: grid 512
  gemm_bt<1, 64><<<dim3(1024 / 64, TOKENS / 128), 256, 0, stream>>>(
      xob, woutT, b_out, TOKENS, 1024, 1024, y, nullptr, x, nullptr, nullptr, nullptr);
  // LN1 -> x1 (fp32 + bf16)
  ln_k<<<TOKENS, 256, 0, stream>>>(y, ln1_g, ln1_b, x1f, x1b);
  // FF1 + GELU
  gemm_bt<2, 128><<<dim3(4096 / 128, TOKENS / 128), 256, 0, stream>>>(
      x1b, wff1T, b_ff1, TOKENS, 4096, 1024, nullptr, hb, nullptr, nullptr, nullptr, nullptr);
  // FF2 + residual (fp32 x1)  — BN=64: grid 512
  gemm_bt<1, 64><<<dim3(1024 / 64, TOKENS / 128), 256, 0, stream>>>(
      hb, wff2T, b_ff2, TOKENS, 1024, 4096, y, nullptr, x1f, nullptr, nullptr, nullptr);
  // LN2 -> d_out
  ln_k<<<TOKENS, 256, 0, stream>>>(y, ln2_g, ln2_b, out, nullptr);
}